// Round 13
// baseline (122.472 us; speedup 1.0000x reference)
//
#include <hip/hip_runtime.h>

// QueryEncDec: 2 stacks x 128 layers of scalar GRU (H=in=1), T=256.
// R13 = R12 (4 waves x 64 lanes, 3-phase loop, DPP handoff w/ old-operand
// feed, hw rcp, flush-every-2, batch-4 reads w/ mid-batch prefetch, pre-spin
// lag 73) + the R12 bug fix: flush predicate now requires tm < T_LEN.
// R12's last flush (s=319, lane 63) computed tm=256 and, on the LAST wave,
// stored to out[256] = dec_h[0], clobbering wave 2's result. Mailbox timing:
// slot t publishes at producer step <= t+64; pre-spin on slot 9 (publishes
// step 73) -> lag >= 73; direct reads need 68, prefetch needs <= 72.
// Critical path: 3*73 + 320 = 539 steps; chain floor ~148 cy/step
// (VALU dep ~8 cy, trans dep ~25 cy -- calibrated R4/R10/R11).

#define T_LEN 256
#define MBOX  320              // 0..255 data slots, 256..319 per-lane dump
typedef unsigned long long u64;
typedef unsigned int u32;

__device__ __forceinline__ float fexp2(float x) { return __builtin_amdgcn_exp2f(x); }
__device__ __forceinline__ float frcp(float x)  { return __builtin_amdgcn_rcpf(x); }

struct CellW {
    float wri, wrh, brc;   // r gate, pre-scaled by -log2(e)
    float wzi, wzh, bzc;   // z gate, pre-scaled by -log2(e)
    float wni, bni;        // n gate input half, pre-scaled by 2*log2(e)
    float wnh, bnh;        // n gate hidden half, pre-scaled by 2*log2(e)
};

__device__ __forceinline__ float cell_step(const CellW& c, float x, float h) {
    // h-leg pre-sums run while x is still in the DPP; x enters 1 fma deep.
    const float hr  = __builtin_fmaf(c.wrh, h, c.brc);
    const float hz  = __builtin_fmaf(c.wzh, h, c.bzc);
    const float ghn = __builtin_fmaf(c.wnh, h, c.bnh);
    const float gin = __builtin_fmaf(c.wni, x, c.bni);
    const float er  = fexp2(__builtin_fmaf(c.wri, x, hr));
    const float ez  = fexp2(__builtin_fmaf(c.wzi, x, hz));
    const float r   = frcp(1.0f + er);
    const float z   = frcp(1.0f + ez);
    const float en  = fexp2(__builtin_fmaf(r, ghn, gin));   // e^{2v}
    const float q   = frcp(1.0f + en);                      // n = 1-2q
    const float A   = __builtin_fmaf(z, h - 1.0f, 1.0f);
    const float B   = __builtin_fmaf(2.0f, z, -2.0f);
    return __builtin_fmaf(q, B, A);                         // (1-z)n + z h
}

template<bool MASKED, bool READ, bool LAST>
__device__ __forceinline__ void do_batch4(
    const int s0, const int j, const int js, const CellW& c,
    volatile u64* inbox, volatile u64* outbox,
    float* __restrict__ out, float* __restrict__ dumpG,
    float& h, float& hcp, u32& coll, u64& bnext)
{
    u32 bval = 0;
    if (READ) {
        const int slot = s0 + js;
        u64 v = bnext;                  // prefetched mid-previous-batch
        while (__ballot((u32)(v >> 32) == (u32)(slot + 1)) != ~0ull)
            v = inbox[slot];            // cold fallback (fill phase only)
        bval = (u32)v;
    }
    #pragma unroll
    for (int si = 0; si < 4; ++si) {
        const int s = s0 + si;
        // lane-0 feed (literal-index readlane); handoff via DPP old-operand
        const int fv = READ ? __builtin_amdgcn_readlane((int)bval, si) : 0;
        const int xm = __builtin_amdgcn_update_dpp(
            fv, __builtin_bit_cast(int, hcp), 0x138 /*wave_shr:1*/, 0xF, 0xF, false);
        const float x = __builtin_bit_cast(float, xm);

        const float hc = cell_step(c, x, h);
        if (MASKED) {
            const int t = s - j;
            h = ((u32)t < (u32)T_LEN) ? hc : h;
        } else {
            h = hc;                     // steady: always in-range
        }
        hcp = hc;

        // mid-batch prefetch: issued ~300 cy before use; lag 73 >= 70 needed
        if (READ && si == 2) {
            if (s0 + 4 < T_LEN) bnext = inbox[s0 + 4 + js];
        }

        // collector: shift history DOWN (lane m <- m+1), insert committed h
        const int cs = __builtin_amdgcn_update_dpp(
            0, (int)coll, 0x130 /*wave_shl:1*/, 0xF, 0xF, false);
        coll = (j == 63) ? __builtin_bit_cast(u32, h) : (u32)cs;

        if (si == 1 || si == 3) {       // flush every 2 steps (compile-time)
            // lane m in 62..63 holds lane-63 h for t = s + m - 126
            const int  tm   = s + j - 126;
            // R12 BUG FIX: require tm < T_LEN (s=319 lane 63 gives tm=256,
            // which on the LAST wave aliased out[256] = dec_h[0]).
            const bool real = (j >= 62) & ((u32)tm < (u32)T_LEN);
            if (!LAST) {
                const int widx = real ? tm : (T_LEN + j);    // dump: 256+j
                outbox[widx] = ((u64)(u32)(tm + 1) << 32) | (u64)coll;
            } else {                    // dec_out: 2-float store / 2 steps
                float* p = real ? (out + tm) : (dumpG + j);
                *p = __builtin_bit_cast(float, coll);
            }
        }
    }
}

template<bool LAST>
__device__ __forceinline__ float run_wave(
    const int j, const CellW& c,
    volatile u64* inbox, volatile u64* outbox,
    float* __restrict__ out, float* __restrict__ dumpG)
{
    float h = 0.0f, hcp = 0.0f;
    u32 coll = 0;
    const int js = j & 3;

    // pre-spin: slot 9 (tag 10) publishes at producer step 73
    // -> lag >= 73 (direct reads need 68, prefetch needs <= 72; slack >= 1).
    // Wave 0's inbox is the pre-tagged X mailbox: passes immediately.
    {
        u64 v = inbox[9];
        while (__ballot((u32)(v >> 32) == 10u) != ~0ull) v = inbox[9];
    }
    u64 bnext = inbox[js];              // batch 0 (published by lag >= 68)

    #pragma unroll 1
    for (int b = 0; b < 16; ++b)        // prologue: s = 0..63 (masked, reads)
        do_batch4<true, true, LAST>(b * 4, j, js, c, inbox, outbox, out, dumpG, h, hcp, coll, bnext);
    #pragma unroll 1
    for (int b = 16; b < 64; ++b)       // steady: s = 64..255 (unmasked, reads)
        do_batch4<false, true, LAST>(b * 4, j, js, c, inbox, outbox, out, dumpG, h, hcp, coll, bnext);
    #pragma unroll 1
    for (int b = 64; b < 80; ++b)       // epilogue: s = 256..319 (masked, no reads)
        do_batch4<true, false, LAST>(b * 4, j, js, c, inbox, outbox, out, dumpG, h, hcp, coll, bnext);

    return h;
}

__global__ __launch_bounds__(256, 1) void gru_pipe13(
    const float* __restrict__ X,
    const float* __restrict__ enc_w_ih, const float* __restrict__ enc_w_hh,
    const float* __restrict__ enc_b_ih, const float* __restrict__ enc_b_hh,
    const float* __restrict__ dec_w_ih, const float* __restrict__ dec_w_hh,
    const float* __restrict__ dec_b_ih, const float* __restrict__ dec_b_hh,
    float* __restrict__ out, float* __restrict__ dumpG)
{
    const int tid = threadIdx.x;        // global layer 0..255
    const int w   = tid >> 6;           // wave 0..3
    const int j   = tid & 63;

    __shared__ u64 xsM[T_LEN];          // X as a pre-tagged mailbox
    __shared__ u64 box[4][MBOX];        // box[3] = wave-3 trash (uniform code path)

    xsM[tid] = ((u64)(u32)(tid + 1) << 32) |
               (u64)__builtin_bit_cast(u32, X[tid]);
    box[0][tid] = 0ull;                 // data slots 0..255 need tag=0
    box[1][tid] = 0ull;
    box[2][tid] = 0ull;
    box[3][tid] = 0ull;

    // per-layer params (torch gate order r,z,n), constants folded
    const int pl = tid & 127;
    const float* wip = (tid < 128) ? enc_w_ih : dec_w_ih;
    const float* whp = (tid < 128) ? enc_w_hh : dec_w_hh;
    const float* bip = (tid < 128) ? enc_b_ih : dec_b_ih;
    const float* bhp = (tid < 128) ? enc_b_hh : dec_b_hh;
    const float L2E = 1.44269504088896340736f;
    CellW c;
    c.wri = -L2E * wip[3 * pl + 0];
    c.wrh = -L2E * whp[3 * pl + 0];
    c.brc = -L2E * (bip[3 * pl + 0] + bhp[3 * pl + 0]);
    c.wzi = -L2E * wip[3 * pl + 1];
    c.wzh = -L2E * whp[3 * pl + 1];
    c.bzc = -L2E * (bip[3 * pl + 1] + bhp[3 * pl + 1]);
    c.wni = 2.0f * L2E * wip[3 * pl + 2];
    c.bni = 2.0f * L2E * bip[3 * pl + 2];
    c.wnh = 2.0f * L2E * whp[3 * pl + 2];
    c.bnh = 2.0f * L2E * bhp[3 * pl + 2];

    __syncthreads();                    // the only block barrier

    volatile u64* inbox  = (w == 0) ? xsM : box[w - 1];
    volatile u64* outbox = box[w];

    float h;
    if (w == 3) h = run_wave<true >(j, c, inbox, outbox, out, dumpG);
    else        h = run_wave<false>(j, c, inbox, outbox, out, dumpG);

    // dec_h: final hidden of decoder layers (global layers 128..255)
    if (w >= 2) out[T_LEN + 64 * (w - 2) + j] = h;
}

extern "C" void kernel_launch(void* const* d_in, const int* in_sizes, int n_in,
                              void* d_out, int out_size, void* d_ws, size_t ws_size,
                              hipStream_t stream) {
    const float* X        = (const float*)d_in[0];
    const float* enc_w_ih = (const float*)d_in[1];
    const float* enc_w_hh = (const float*)d_in[2];
    const float* enc_b_ih = (const float*)d_in[3];
    const float* enc_b_hh = (const float*)d_in[4];
    const float* dec_w_ih = (const float*)d_in[5];
    const float* dec_w_hh = (const float*)d_in[6];
    const float* dec_b_ih = (const float*)d_in[7];
    const float* dec_b_hh = (const float*)d_in[8];
    float* out = (float*)d_out;
    float* dumpG = (float*)d_ws;

    gru_pipe13<<<1, 256, 0, stream>>>(X,
                                      enc_w_ih, enc_w_hh, enc_b_ih, enc_b_hh,
                                      dec_w_ih, dec_w_hh, dec_b_ih, dec_b_hh,
                                      out, dumpG);
}

// Round 14
// 112.198 us; speedup vs baseline: 1.0916x; 1.0916x over previous
//
#include <hip/hip_runtime.h>

// QueryEncDec: 2 stacks x 128 layers of scalar GRU (H=in=1), T=256.
// R14 = R10 (best measured: 4 waves x 64 lanes, batch-8 mailbox reads,
// flush every 4 steps at si==2/6 via lanes 60..63, 3-phase loop, DPP handoff
// w/ old-operand feed, hw rcp) + ONE change: the next batch's ds_read_b64 is
// prefetched at si==4 (~600 cy before its ballot, clear of both flush writes)
// so the batch-boundary LDS latency is off the critical path.
// Timing: slot t publishes in [t+63, t+66] (one flush step in any 4-window);
// prefetch of slot s0+8+js at consumer step s0+4 needs lag >= 70+js <= 77;
// pre-spin on slot 14 (publishes at producer step 78 = 6 mod 8) -> lag >= 78.
// Critical path: 3*78 + 320 = 554 steps. R13 post-mortem: batch-4 doubled
// boundary waitcnt drains (and flush-2 put a fresh ds_write right before
// each drain) -- batch-8 + flush-4 cadence is retained unchanged.

#define T_LEN 256
#define MBOX  320              // 0..255 data slots, 256..319 per-lane dump
typedef unsigned long long u64;
typedef unsigned int u32;

__device__ __forceinline__ float fexp2(float x) { return __builtin_amdgcn_exp2f(x); }
__device__ __forceinline__ float frcp(float x)  { return __builtin_amdgcn_rcpf(x); }

struct CellW {
    float wri, wrh, brc;   // r gate, pre-scaled by -log2(e)
    float wzi, wzh, bzc;   // z gate, pre-scaled by -log2(e)
    float wni, bni;        // n gate input half, pre-scaled by 2*log2(e)
    float wnh, bnh;        // n gate hidden half, pre-scaled by 2*log2(e)
};

__device__ __forceinline__ float cell_step(const CellW& c, float x, float h) {
    // h-leg pre-sums run while x is still in the DPP; x enters 1 fma deep.
    const float hr  = __builtin_fmaf(c.wrh, h, c.brc);
    const float hz  = __builtin_fmaf(c.wzh, h, c.bzc);
    const float ghn = __builtin_fmaf(c.wnh, h, c.bnh);
    const float gin = __builtin_fmaf(c.wni, x, c.bni);
    const float er  = fexp2(__builtin_fmaf(c.wri, x, hr));
    const float ez  = fexp2(__builtin_fmaf(c.wzi, x, hz));
    const float r   = frcp(1.0f + er);
    const float z   = frcp(1.0f + ez);
    const float en  = fexp2(__builtin_fmaf(r, ghn, gin));   // e^{2v}
    const float q   = frcp(1.0f + en);                      // n = 1-2q
    const float A   = __builtin_fmaf(z, h - 1.0f, 1.0f);
    const float B   = __builtin_fmaf(2.0f, z, -2.0f);
    return __builtin_fmaf(q, B, A);                         // (1-z)n + z h
}

template<bool MASKED, bool READ, bool LAST>
__device__ __forceinline__ void do_batch8(
    const int s0, const int j, const int js, const CellW& c,
    volatile u64* inbox, volatile u64* outbox,
    float* __restrict__ out, float* __restrict__ dumpG,
    float& h, float& hcp, u32& coll, u64& bnext)
{
    u32 bval = 0;
    if (READ) {                         // validated via prefetched value
        const int slot = s0 + js;
        u64 v = bnext;                  // issued at si==4 of the previous batch
        while (__ballot((u32)(v >> 32) == (u32)(slot + 1)) != ~0ull)
            v = inbox[slot];            // cold fallback (fill phase only)
        bval = (u32)v;
    }
    #pragma unroll
    for (int si = 0; si < 8; ++si) {
        const int s = s0 + si;
        // lane-0 feed (literal-index readlane); handoff via DPP old-operand
        const int fv = READ ? __builtin_amdgcn_readlane((int)bval, si) : 0;
        const int xm = __builtin_amdgcn_update_dpp(
            fv, __builtin_bit_cast(int, hcp), 0x138 /*wave_shr:1*/, 0xF, 0xF, false);
        const float x = __builtin_bit_cast(float, xm);

        const float hc = cell_step(c, x, h);
        if (MASKED) {
            const int t = s - j;
            h = ((u32)t < (u32)T_LEN) ? hc : h;
        } else {
            h = hc;                     // steady: always in-range
        }
        hcp = hc;

        // prefetch next batch's slot: ~600 cy of lead, clear of both flushes
        if (READ && si == 4) {
            if (s0 + 8 < T_LEN) bnext = inbox[s0 + 8 + js];
        }

        // collector: shift history DOWN (lane m <- m+1), insert committed h
        const int cs = __builtin_amdgcn_update_dpp(
            0, (int)coll, 0x130 /*wave_shl:1*/, 0xF, 0xF, false);
        coll = (j == 63) ? __builtin_bit_cast(u32, h) : (u32)cs;

        if (si == 2 || si == 6) {       // flush every 4 steps (compile-time)
            // lane m in 60..63 holds lane-63 h for t = s + m - 126
            const int  tm   = s + j - 126;
            const bool real = (j >= 60) & ((u32)tm < (u32)T_LEN);
            if (!LAST) {
                const int widx = real ? tm : (T_LEN + j);    // dump: 256+j
                outbox[widx] = ((u64)(u32)(tm + 1) << 32) | (u64)coll;
            } else {                    // dec_out: coalesced 4-float store
                float* p = real ? (out + tm) : (dumpG + j);
                *p = __builtin_bit_cast(float, coll);
            }
        }
    }
}

template<bool LAST>
__device__ __forceinline__ float run_wave(
    const int j, const CellW& c,
    volatile u64* inbox, volatile u64* outbox,
    float* __restrict__ out, float* __restrict__ dumpG)
{
    float h = 0.0f, hcp = 0.0f;
    u32 coll = 0;
    const int js = j & 7;

    // pre-spin: slot 14 publishes at producer step 78 (78 = 6 mod 8) ->
    // lag >= 78 (direct reads need <= 73, prefetch needs <= 77; slack >= 1).
    // Wave 0's inbox is the pre-tagged X mailbox: passes immediately.
    {
        u64 v = inbox[14];
        while (__ballot((u32)(v >> 32) == 15u) != ~0ull) v = inbox[14];
    }
    u64 bnext = inbox[js];              // batch 0 (published by lag >= 73)

    #pragma unroll 1
    for (int b = 0; b < 8; ++b)         // prologue: s = 0..63 (masked, reads)
        do_batch8<true, true, LAST>(b * 8, j, js, c, inbox, outbox, out, dumpG, h, hcp, coll, bnext);
    #pragma unroll 1
    for (int b = 8; b < 32; ++b)        // steady: s = 64..255 (unmasked, reads)
        do_batch8<false, true, LAST>(b * 8, j, js, c, inbox, outbox, out, dumpG, h, hcp, coll, bnext);
    #pragma unroll 1
    for (int b = 32; b < 40; ++b)       // epilogue: s = 256..319 (masked, no reads)
        do_batch8<true, false, LAST>(b * 8, j, js, c, inbox, outbox, out, dumpG, h, hcp, coll, bnext);

    return h;
}

__global__ __launch_bounds__(256, 1) void gru_pipe14(
    const float* __restrict__ X,
    const float* __restrict__ enc_w_ih, const float* __restrict__ enc_w_hh,
    const float* __restrict__ enc_b_ih, const float* __restrict__ enc_b_hh,
    const float* __restrict__ dec_w_ih, const float* __restrict__ dec_w_hh,
    const float* __restrict__ dec_b_ih, const float* __restrict__ dec_b_hh,
    float* __restrict__ out, float* __restrict__ dumpG)
{
    const int tid = threadIdx.x;        // global layer 0..255
    const int w   = tid >> 6;           // wave 0..3
    const int j   = tid & 63;

    __shared__ u64 xsM[T_LEN];          // X as a pre-tagged mailbox
    __shared__ u64 box[4][MBOX];        // box[3] = wave-3 trash (uniform code path)

    xsM[tid] = ((u64)(u32)(tid + 1) << 32) |
               (u64)__builtin_bit_cast(u32, X[tid]);
    box[0][tid] = 0ull;                 // data slots 0..255 need tag=0
    box[1][tid] = 0ull;
    box[2][tid] = 0ull;
    box[3][tid] = 0ull;

    // per-layer params (torch gate order r,z,n), constants folded
    const int pl = tid & 127;
    const float* wip = (tid < 128) ? enc_w_ih : dec_w_ih;
    const float* whp = (tid < 128) ? enc_w_hh : dec_w_hh;
    const float* bip = (tid < 128) ? enc_b_ih : dec_b_ih;
    const float* bhp = (tid < 128) ? enc_b_hh : dec_b_hh;
    const float L2E = 1.44269504088896340736f;
    CellW c;
    c.wri = -L2E * wip[3 * pl + 0];
    c.wrh = -L2E * whp[3 * pl + 0];
    c.brc = -L2E * (bip[3 * pl + 0] + bhp[3 * pl + 0]);
    c.wzi = -L2E * wip[3 * pl + 1];
    c.wzh = -L2E * whp[3 * pl + 1];
    c.bzc = -L2E * (bip[3 * pl + 1] + bhp[3 * pl + 1]);
    c.wni = 2.0f * L2E * wip[3 * pl + 2];
    c.bni = 2.0f * L2E * bip[3 * pl + 2];
    c.wnh = 2.0f * L2E * whp[3 * pl + 2];
    c.bnh = 2.0f * L2E * bhp[3 * pl + 2];

    __syncthreads();                    // the only block barrier

    volatile u64* inbox  = (w == 0) ? xsM : box[w - 1];
    volatile u64* outbox = box[w];

    float h;
    if (w == 3) h = run_wave<true >(j, c, inbox, outbox, out, dumpG);
    else        h = run_wave<false>(j, c, inbox, outbox, out, dumpG);

    // dec_h: final hidden of decoder layers (global layers 128..255)
    if (w >= 2) out[T_LEN + 64 * (w - 2) + j] = h;
}

extern "C" void kernel_launch(void* const* d_in, const int* in_sizes, int n_in,
                              void* d_out, int out_size, void* d_ws, size_t ws_size,
                              hipStream_t stream) {
    const float* X        = (const float*)d_in[0];
    const float* enc_w_ih = (const float*)d_in[1];
    const float* enc_w_hh = (const float*)d_in[2];
    const float* enc_b_ih = (const float*)d_in[3];
    const float* enc_b_hh = (const float*)d_in[4];
    const float* dec_w_ih = (const float*)d_in[5];
    const float* dec_w_hh = (const float*)d_in[6];
    const float* dec_b_ih = (const float*)d_in[7];
    const float* dec_b_hh = (const float*)d_in[8];
    float* out = (float*)d_out;
    float* dumpG = (float*)d_ws;

    gru_pipe14<<<1, 256, 0, stream>>>(X,
                                      enc_w_ih, enc_w_hh, enc_b_ih, enc_b_hh,
                                      dec_w_ih, dec_w_hh, dec_b_ih, dec_b_hh,
                                      out, dumpG);
}

// Round 15
// 106.770 us; speedup vs baseline: 1.1471x; 1.0508x over previous
//
#include <hip/hip_runtime.h>

// QueryEncDec: 2 stacks x 128 layers of scalar GRU (H=in=1), T=256.
// FINAL (R15) = R10 verbatim -- the best-measured configuration:
//  - 4 waves x 64 lanes, 1 layer/lane; wavefront schedule, 542-step path.
//  - Intra-wave handoff: single DPP wave_shr:1, old-operand carries the
//    lane-0 feed (no cndmask on the inter-lane chain).
//  - Cross-wave handoff: tagged-u64 LDS mailbox; batch-8 reads validated by
//    one __ballot; producer collects lane-63 h via DPP wave_shl:1 and lanes
//    60..63 flush 4 tagged slots per 4 steps (si==2/6).
//  - 3-phase loop: prologue (masked)/steady (no commit cndmask)/epilogue.
//  - Hardware rcp/exp2 (gate constants folded into weights).
// Post-mortems R11-R14: batch-4, flush-2, Newton rcp, and mid-batch prefetch
// each regress (LDS ops/waitcnts pulled into the dependent loop body).
// Inter-lane dependence cycle ~165 cy; DAG floor ~511x165 ~ 35 us; this
// kernel: 542 steps x ~193 cy ~ 43.7 us rocprof -- the HIP-level optimum
// found for this latency-bound (1-CU, chain-dominated) problem.

#define T_LEN 256
#define MBOX  320              // 0..255 data slots, 256..319 per-lane dump
typedef unsigned long long u64;
typedef unsigned int u32;

__device__ __forceinline__ float fexp2(float x) { return __builtin_amdgcn_exp2f(x); }
__device__ __forceinline__ float frcp(float x)  { return __builtin_amdgcn_rcpf(x); }

struct CellW {
    float wri, wrh, brc;   // r gate, pre-scaled by -log2(e)
    float wzi, wzh, bzc;   // z gate, pre-scaled by -log2(e)
    float wni, bni;        // n gate input half, pre-scaled by 2*log2(e)
    float wnh, bnh;        // n gate hidden half, pre-scaled by 2*log2(e)
};

__device__ __forceinline__ float cell_step(const CellW& c, float x, float h) {
    // h-leg pre-sums run while x is still in the DPP; x enters 1 fma deep.
    const float hr  = __builtin_fmaf(c.wrh, h, c.brc);
    const float hz  = __builtin_fmaf(c.wzh, h, c.bzc);
    const float ghn = __builtin_fmaf(c.wnh, h, c.bnh);
    const float gin = __builtin_fmaf(c.wni, x, c.bni);
    const float er  = fexp2(__builtin_fmaf(c.wri, x, hr));
    const float ez  = fexp2(__builtin_fmaf(c.wzi, x, hz));
    const float r   = frcp(1.0f + er);
    const float z   = frcp(1.0f + ez);
    const float en  = fexp2(__builtin_fmaf(r, ghn, gin));   // e^{2v}
    const float q   = frcp(1.0f + en);                      // n = 1-2q
    const float A   = __builtin_fmaf(z, h - 1.0f, 1.0f);
    const float B   = __builtin_fmaf(2.0f, z, -2.0f);
    return __builtin_fmaf(q, B, A);                         // (1-z)n + z h
}

template<bool MASKED, bool READ, bool LAST>
__device__ __forceinline__ void do_batch(
    const int s0, const int j, const int js, const CellW& c,
    volatile u64* inbox, volatile u64* outbox,
    float* __restrict__ out, float* __restrict__ dumpG,
    float& h, float& hcp, u32& coll)
{
    u32 bval = 0;
    if (READ) {                         // one ds_read_b64 + one ballot / 8 steps
        const int slot = s0 + js;
        u64 v = inbox[slot];
        while (__ballot((u32)(v >> 32) == (u32)(slot + 1)) != ~0ull)
            v = inbox[slot];            // fallback; first-try pass in steady state
        bval = (u32)v;
    }
    #pragma unroll
    for (int si = 0; si < 8; ++si) {
        const int s = s0 + si;
        // lane-0 feed (literal-index readlane); handoff via DPP old-operand
        const int fv = READ ? __builtin_amdgcn_readlane((int)bval, si) : 0;
        const int xm = __builtin_amdgcn_update_dpp(
            fv, __builtin_bit_cast(int, hcp), 0x138 /*wave_shr:1*/, 0xF, 0xF, false);
        const float x = __builtin_bit_cast(float, xm);

        const float hc = cell_step(c, x, h);
        if (MASKED) {
            const int t = s - j;
            h = ((u32)t < (u32)T_LEN) ? hc : h;
        } else {
            h = hc;                     // steady: always in-range, no cndmask
        }
        hcp = hc;

        // collector: shift history DOWN (lane m <- m+1), insert committed h
        const int cs = __builtin_amdgcn_update_dpp(
            0, (int)coll, 0x130 /*wave_shl:1*/, 0xF, 0xF, false);
        coll = (j == 63) ? __builtin_bit_cast(u32, h) : (u32)cs;

        if (si == 2 || si == 6) {       // flush every 4 steps (compile-time)
            // lane m in 60..63 holds lane-63 h for t = s + m - 126
            const int  tm   = s + j - 126;
            const bool real = (j >= 60) & (tm >= 0);
            if (!LAST) {
                const int widx = real ? tm : (T_LEN + j);    // dump: 256+j
                outbox[widx] = ((u64)(u32)(tm + 1) << 32) | (u64)coll;
            } else {                    // dec_out: coalesced 4-float store
                float* p = real ? (out + tm) : (dumpG + j);
                *p = __builtin_bit_cast(float, coll);
            }
        }
    }
}

template<bool LAST>
__device__ __forceinline__ float run_wave(
    const int j, const CellW& c,
    volatile u64* inbox, volatile u64* outbox,
    float* __restrict__ out, float* __restrict__ dumpG)
{
    float h = 0.0f, hcp = 0.0f;
    u32 coll = 0;
    const int js = j & 7;

    // pre-spin: slot 11 (tag 12) is published at producer local step 74 ->
    // lag >= 74; batch s0 needs slot s0+7 by step s0+73 -> first-try passes.
    // Wave 0's inbox is the pre-tagged X mailbox: passes immediately.
    {
        u64 v = inbox[11];
        while (__ballot((u32)(v >> 32) == 12u) != ~0ull) v = inbox[11];
    }

    #pragma unroll 1
    for (int b = 0; b < 8; ++b)         // prologue: s = 0..63 (masked, reads)
        do_batch<true, true, LAST>(b * 8, j, js, c, inbox, outbox, out, dumpG, h, hcp, coll);
    #pragma unroll 1
    for (int b = 8; b < 32; ++b)        // steady: s = 64..255 (unmasked, reads)
        do_batch<false, true, LAST>(b * 8, j, js, c, inbox, outbox, out, dumpG, h, hcp, coll);
    #pragma unroll 1
    for (int b = 32; b < 40; ++b)       // epilogue: s = 256..319 (masked, no reads)
        do_batch<true, false, LAST>(b * 8, j, js, c, inbox, outbox, out, dumpG, h, hcp, coll);

    return h;
}

__global__ __launch_bounds__(256, 1) void gru_pipe15(
    const float* __restrict__ X,
    const float* __restrict__ enc_w_ih, const float* __restrict__ enc_w_hh,
    const float* __restrict__ enc_b_ih, const float* __restrict__ enc_b_hh,
    const float* __restrict__ dec_w_ih, const float* __restrict__ dec_w_hh,
    const float* __restrict__ dec_b_ih, const float* __restrict__ dec_b_hh,
    float* __restrict__ out, float* __restrict__ dumpG)
{
    const int tid = threadIdx.x;        // global layer 0..255
    const int w   = tid >> 6;           // wave 0..3
    const int j   = tid & 63;

    __shared__ u64 xsM[T_LEN];          // X as a pre-tagged mailbox
    __shared__ u64 box[4][MBOX];        // box[3] = wave-3 trash (uniform code path)

    xsM[tid] = ((u64)(u32)(tid + 1) << 32) |
               (u64)__builtin_bit_cast(u32, X[tid]);
    box[0][tid] = 0ull;                 // data slots 0..255 need tag=0
    box[1][tid] = 0ull;
    box[2][tid] = 0ull;
    box[3][tid] = 0ull;

    // per-layer params (torch gate order r,z,n), constants folded
    const int pl = tid & 127;
    const float* wip = (tid < 128) ? enc_w_ih : dec_w_ih;
    const float* whp = (tid < 128) ? enc_w_hh : dec_w_hh;
    const float* bip = (tid < 128) ? enc_b_ih : dec_b_ih;
    const float* bhp = (tid < 128) ? enc_b_hh : dec_b_hh;
    const float L2E = 1.44269504088896340736f;
    CellW c;
    c.wri = -L2E * wip[3 * pl + 0];
    c.wrh = -L2E * whp[3 * pl + 0];
    c.brc = -L2E * (bip[3 * pl + 0] + bhp[3 * pl + 0]);
    c.wzi = -L2E * wip[3 * pl + 1];
    c.wzh = -L2E * whp[3 * pl + 1];
    c.bzc = -L2E * (bip[3 * pl + 1] + bhp[3 * pl + 1]);
    c.wni = 2.0f * L2E * wip[3 * pl + 2];
    c.bni = 2.0f * L2E * bip[3 * pl + 2];
    c.wnh = 2.0f * L2E * whp[3 * pl + 2];
    c.bnh = 2.0f * L2E * bhp[3 * pl + 2];

    __syncthreads();                    // the only block barrier

    volatile u64* inbox  = (w == 0) ? xsM : box[w - 1];
    volatile u64* outbox = box[w];

    float h;
    if (w == 3) h = run_wave<true >(j, c, inbox, outbox, out, dumpG);
    else        h = run_wave<false>(j, c, inbox, outbox, out, dumpG);

    // dec_h: final hidden of decoder layers (global layers 128..255)
    if (w >= 2) out[T_LEN + 64 * (w - 2) + j] = h;
}

extern "C" void kernel_launch(void* const* d_in, const int* in_sizes, int n_in,
                              void* d_out, int out_size, void* d_ws, size_t ws_size,
                              hipStream_t stream) {
    const float* X        = (const float*)d_in[0];
    const float* enc_w_ih = (const float*)d_in[1];
    const float* enc_w_hh = (const float*)d_in[2];
    const float* enc_b_ih = (const float*)d_in[3];
    const float* enc_b_hh = (const float*)d_in[4];
    const float* dec_w_ih = (const float*)d_in[5];
    const float* dec_w_hh = (const float*)d_in[6];
    const float* dec_b_ih = (const float*)d_in[7];
    const float* dec_b_hh = (const float*)d_in[8];
    float* out = (float*)d_out;
    float* dumpG = (float*)d_ws;

    gru_pipe15<<<1, 256, 0, stream>>>(X,
                                      enc_w_ih, enc_w_hh, enc_b_ih, enc_b_hh,
                                      dec_w_ih, dec_w_hh, dec_b_ih, dec_b_hh,
                                      out, dumpG);
}